// Round 13
// baseline (106.786 us; speedup 1.0000x reference)
//
#include <hip/hip_runtime.h>
#include <hip/hip_bf16.h>

// NT-Xent loss, BS=4096, D=256, TAU=0.5.
// R13 = R12 (best, 86.2us) + MEASUREMENT PROBE: kgemm launched TWICE
// (idempotent -> still correct). dur_us delta vs R12 = t_kgemm, resolving
// the Model A (kgemm ~10us, at floor) vs Model B (kgemm ~30us, 2x win
// available) ambiguity that subtractive inference couldn't.
//
// znsw layout (fragment-native for mfma_f32_16x16x32_fp8_fp8):
//   16-row group rg, chunk-pair kbp (0..3): 64 lanes x 16B at
//   byte ((rg*4+kbp)*64 + fl)*16. Lane fl: row = rg*16 + (fl&15),
//   low 8B  = k = (2*kbp+0)*32 + (fl>>4)*8+j, high 8B same with +32.
// A 128-row panel (8 rgs) = 32KB contiguous.

#define N_ROWS 8192
#define BSZ    4096
#define DIM    256
#define INV_TAU 2.0f
#define EPS_REF 1e-8f
#define COS_EPS 1e-8f
#define NG2     64                     // 128-row groups
#define NTILES  (NG2 * (NG2 + 1) / 2)  // 2080 triangular tiles
#define LSTRIDE 260                    // padded floats per row in knorm LDS

typedef __attribute__((ext_vector_type(4))) float f32x4;
typedef long long i64;
typedef union { int4 v; i64 d[2]; } pack16;

// sum across each 16-lane group via DPP row_ror (VALU pipe, no LDS traffic)
__device__ __forceinline__ float red16(float x) {
    x += __int_as_float(__builtin_amdgcn_update_dpp(0, __float_as_int(x), 0x121, 0xf, 0xf, false));
    x += __int_as_float(__builtin_amdgcn_update_dpp(0, __float_as_int(x), 0x122, 0xf, 0xf, false));
    x += __int_as_float(__builtin_amdgcn_update_dpp(0, __float_as_int(x), 0x124, 0xf, 0xf, false));
    x += __int_as_float(__builtin_amdgcn_update_dpp(0, __float_as_int(x), 0x128, 0xf, 0xf, false));
    return x;
}

// ---------------- Kernel 1: normalize + fp8 quantize + fragment swizzle -----
__global__ __launch_bounds__(256) void knorm(const float* __restrict__ zi,
                                             const float* __restrict__ zj,
                                             unsigned char* __restrict__ znsw,
                                             float* __restrict__ out) {
    __shared__ float lds[16 * LSTRIDE];
    __shared__ float nrm[16];
    const int rg = blockIdx.x;     // 0..511: 16-row group
    const int t  = threadIdx.x;
    const int w  = t >> 6;
    const int l  = t & 63;
    const int row0 = rg * 16;
    if (rg == 0 && t == 0) out[0] = 0.f;    // kfinal atomics run after us

    // load + register norms: iteration s -> row 4s+w, cols l*4..l*4+3
    #pragma unroll
    for (int s = 0; s < 4; ++s) {
        const int row = s * 4 + w;
        const int r   = row0 + row;
        const float* src = (r < BSZ) ? zi + (size_t)r * DIM + l * 4
                                     : zj + (size_t)(r - BSZ) * DIM + l * 4;
        const float4 v = *(const float4*)src;
        *(float4*)&lds[row * LSTRIDE + l * 4] = v;
        float ss = v.x*v.x + v.y*v.y + v.z*v.z + v.w*v.w;
        #pragma unroll
        for (int off = 32; off >= 1; off >>= 1) ss += __shfl_xor(ss, off);
        if (l == 0) nrm[row] = 1.0f / fmaxf(sqrtf(ss), COS_EPS);
    }
    __syncthreads();

    // quantize: wave w emits chunk-pair kbp=w; lane fl -> row fl&15.
    const int kbp = w, fl = l;
    const int r16 = fl & 15, q = fl >> 4;
    const float inv = nrm[r16];
    int wd[4];
    #pragma unroll
    for (int h = 0; h < 2; ++h) {
        const int kk = (2 * kbp + h) * 32 + q * 8;
        float f[8];
        #pragma unroll
        for (int j = 0; j < 8; ++j) f[j] = lds[r16 * LSTRIDE + kk + j] * inv;
        int a = 0, b = 0;
        a = __builtin_amdgcn_cvt_pk_fp8_f32(f[0], f[1], a, false);
        a = __builtin_amdgcn_cvt_pk_fp8_f32(f[2], f[3], a, true);
        b = __builtin_amdgcn_cvt_pk_fp8_f32(f[4], f[5], b, false);
        b = __builtin_amdgcn_cvt_pk_fp8_f32(f[6], f[7], b, true);
        wd[h * 2] = a; wd[h * 2 + 1] = b;
    }
    *(int4*)(znsw + ((size_t)(rg * 4 + kbp) * 64 + fl) * 16) =
        make_int4(wd[0], wd[1], wd[2], wd[3]);
}

// ---------------- Kernel 2: triangular Gram; A staged, B direct -------------
__global__ __launch_bounds__(256, 4) void kgemm(const unsigned char* __restrict__ znsw,
                                                float* __restrict__ P,
                                                float* __restrict__ selfdot,
                                                float* __restrict__ pairdot) {
    __shared__ __align__(16) unsigned char pan[32768];   // A panel only
    const int w = threadIdx.x >> 6;
    const int l = threadIdx.x & 63;

    // triangular decode over NG2=64: S(G) = G*(129-G)/2
    const int t = blockIdx.x;
    int Gi = (int)((129.0f - sqrtf(16641.0f - 8.0f * (float)t)) * 0.5f);
    while ((Gi + 1) * (129 - (Gi + 1)) / 2 <= t) ++Gi;
    while (Gi * (129 - Gi) / 2 > t) --Gi;
    const int Gj = Gi + (t - Gi * (129 - Gi) / 2);

    // stage A panel (32KB, all of K): 1:1 contiguous copy, 8 issues/thread
    const char* srcA = (const char*)znsw + (size_t)Gi * 32768;
    #pragma unroll
    for (int sub = 0; sub < 8; ++sub) {
        const int off = sub * 4096 + w * 1024;
        __builtin_amdgcn_global_load_lds(
            (const __attribute__((address_space(1))) void*)(srcA + off + l * 16),
            (__attribute__((address_space(3))) void*)(&pan[off]), 16, 0, 0);
    }

    // quadrant: rows (w>>1)*64 of A, cols (w&1)*64 of B
    const int rh = w >> 1, ch = w & 1;
    const char* Ap    = (const char*)&pan[0] + rh * 16384 + l * 16;
    const char* bbase = (const char*)znsw + (size_t)Gj * 32768 + ch * 16384 + l * 16;

    // B kbp=0 fragments issued before the barrier (drained together)
    pack16 Bcur[4], Bnxt[4];
    #pragma unroll
    for (int nt = 0; nt < 4; ++nt)
        Bcur[nt].v = *(const int4*)(bbase + nt * 4096);

    f32x4 acc[4][4];
    #pragma unroll
    for (int mt = 0; mt < 4; ++mt)
        #pragma unroll
        for (int nt = 0; nt < 4; ++nt)
            acc[mt][nt] = (f32x4){0.f, 0.f, 0.f, 0.f};

    __syncthreads();   // A staged (and Bcur in flight -> drained here too)

    #pragma unroll
    for (int kbp = 0; kbp < 4; ++kbp) {
        if (kbp < 3) {
            #pragma unroll
            for (int nt = 0; nt < 4; ++nt)
                Bnxt[nt].v = *(const int4*)(bbase + nt * 4096 + (kbp + 1) * 1024);
        }
        pack16 Afr[4];
        #pragma unroll
        for (int mt = 0; mt < 4; ++mt)
            Afr[mt].v = *(const int4*)(Ap + mt * 4096 + kbp * 1024);
        #pragma unroll
        for (int mt = 0; mt < 4; ++mt)
            #pragma unroll
            for (int nt = 0; nt < 4; ++nt) {
                acc[mt][nt] = __builtin_amdgcn_mfma_f32_16x16x32_fp8_fp8(
                    Afr[mt].d[0], Bcur[nt].d[0], acc[mt][nt], 0, 0, 0);
                acc[mt][nt] = __builtin_amdgcn_mfma_f32_16x16x32_fp8_fp8(
                    Afr[mt].d[1], Bcur[nt].d[1], acc[mt][nt], 0, 0, 0);
            }
        #pragma unroll
        for (int nt = 0; nt < 4; ++nt) Bcur[nt] = Bnxt[nt];
    }

    // ---- wave-local epilogue (C/D layout: col = l&15, row = (l>>4)*4+reg) ----
    const int c = l & 15, q = l >> 4;
    const int rsel = c - 4 * q;
    const bool vld = (rsel >= 0) && (rsel < 4);

    // self/pair diagonals live in quadrants with rh==ch
    if ((Gi == Gj || Gj == Gi + 32) && rh == ch) {
        float dv[4];
        #pragma unroll
        for (int mt = 0; mt < 4; ++mt) {
            float d = acc[mt][mt][0];
            #pragma unroll
            for (int r = 1; r < 4; ++r)
                if (rsel == r) d = acc[mt][mt][r];
            dv[mt] = d;
        }
        if (vld) {
            float* dst = (Gi == Gj) ? selfdot : pairdot;
            #pragma unroll
            for (int mt = 0; mt < 4; ++mt)
                dst[Gi * 128 + rh * 64 + mt * 16 + c] = dv[mt];
        }
    }

    #pragma unroll
    for (int mt = 0; mt < 4; ++mt)
        #pragma unroll
        for (int nt = 0; nt < 4; ++nt)
            #pragma unroll
            for (int r = 0; r < 4; ++r)
                acc[mt][nt][r] = __expf(acc[mt][nt][r] * INV_TAU);

    // row sums (DPP reduce across 16 col lanes) -> P[Gj*2+ch][...]
    float rs[4][4];
    #pragma unroll
    for (int mt = 0; mt < 4; ++mt)
        #pragma unroll
        for (int r = 0; r < 4; ++r)
            rs[mt][r] = red16(acc[mt][0][r] + acc[mt][1][r] + acc[mt][2][r] + acc[mt][3][r]);
    if (c == 0) {
        #pragma unroll
        for (int mt = 0; mt < 4; ++mt) {
            const f32x4 o4 = (f32x4){rs[mt][0], rs[mt][1], rs[mt][2], rs[mt][3]};
            __builtin_nontemporal_store(o4,
                (f32x4*)&P[(size_t)(Gj * 2 + ch) * N_ROWS + Gi * 128 + rh * 64 + mt * 16 + q * 4]);
        }
    }

    // col sums (strictly-upper blocks) -> P[Gi*2+rh][Gj*128 + ch*64 + ...]
    if (Gi != Gj) {
        float cs[4];
        #pragma unroll
        for (int nt = 0; nt < 4; ++nt) {
            float s = 0.f;
            #pragma unroll
            for (int mt = 0; mt < 4; ++mt)
                #pragma unroll
                for (int r = 0; r < 4; ++r)
                    s += acc[mt][nt][r];
            s += __shfl_xor(s, 16);
            s += __shfl_xor(s, 32);
            cs[nt] = s;
        }
        if (q == 0) {
            #pragma unroll
            for (int nt = 0; nt < 4; ++nt)
                __builtin_nontemporal_store(cs[nt],
                    &P[(size_t)(Gi * 2 + rh) * N_ROWS + Gj * 128 + ch * 64 + nt * 16 + c]);
        }
    }
}

// ---------------- Kernel 3: per-row loss (latency-hiding) -------------------
__global__ __launch_bounds__(256) void kfinal(const float* __restrict__ P,
                                              const float* __restrict__ selfdot,
                                              const float* __restrict__ pairdot,
                                              float* __restrict__ out) {
    const int l = threadIdx.x & 63;        // row within block
    const int w = threadIdx.x >> 6;        // strip quarter
    const int row = blockIdx.x * 64 + l;
    float s = 0.f;
    #pragma unroll
    for (int st = 0; st < 32; ++st)
        s += P[(size_t)(w * 32 + st) * N_ROWS + row];
    __shared__ float wsum[4][64];
    wsum[w][l] = s;
    __syncthreads();
    if (w == 0) {
        const float tot = wsum[0][l] + wsum[1][l] + wsum[2][l] + wsum[3][l];
        const float selfe = __expf(selfdot[row] * INV_TAU);
        const float pd    = pairdot[(row < BSZ) ? row : row - BSZ];
        float loss = logf(tot - selfe + EPS_REF) - pd * INV_TAU;
        #pragma unroll
        for (int off = 32; off >= 1; off >>= 1) loss += __shfl_xor(loss, off);
        if (l == 0) atomicAdd(out, loss * (1.0f / (float)N_ROWS));
    }
}

extern "C" void kernel_launch(void* const* d_in, const int* in_sizes, int n_in,
                              void* d_out, int out_size, void* d_ws, size_t ws_size,
                              hipStream_t stream) {
    const float* zi = (const float*)d_in[0];
    const float* zj = (const float*)d_in[1];
    float* out = (float*)d_out;

    char* ws = (char*)d_ws;
    unsigned char* znsw = (unsigned char*)ws;                       // 2 MB
    float* P       = (float*)(ws + 2 * 1024 * 1024);                // 4 MB
    float* selfdot = (float*)(ws + 6 * 1024 * 1024);                // 32 KB
    float* pairdot = (float*)(ws + 6 * 1024 * 1024 + 32 * 1024);    // 16 KB

    knorm <<<N_ROWS / 16, 256, 0, stream>>>(zi, zj, znsw, out);
    // PROBE: kgemm twice (idempotent). dur_us - 86.2 = t_kgemm.
    kgemm <<<NTILES, 256, 0, stream>>>(znsw, P, selfdot, pairdot);
    kgemm <<<NTILES, 256, 0, stream>>>(znsw, P, selfdot, pairdot);
    kfinal<<<N_ROWS / 64, 256, 0, stream>>>(P, selfdot, pairdot, out);
}

// Round 14
// 82.942 us; speedup vs baseline: 1.2875x; 1.2875x over previous
//
#include <hip/hip_runtime.h>
#include <hip/hip_bf16.h>

// NT-Xent loss, BS=4096, D=256, TAU=0.5.
// R14 = R12 + MX-scaled fp8 MFMA (16x16x128 f8f6f4, unit scales = plain
// e4m3 math at 2x rate, 4x fewer MFMA instructions). R13's probe measured
// kgemm = 20.6us vs an 8.5us non-scaled-fp8 MFMA-pipe floor (41% busy,
// structure-invariant) -- this halves the floor to ~3.7us.
//
// znsw layout (fragment-native for mfma_scale_f32_16x16x128_f8f6f4,
// assumed lane map: row = l&15, k = (l>>4)*32 + 0..31 per K=128 half):
//   16-row group rg (4096 B): piece pi (0..3) = h*2 + p (h = K-half,
//   p = 16-byte sub-piece): byte rg*4096 + pi*1024 + l*16 holds
//   row = rg*16 + (l&15), k = h*128 + (l>>4)*32 + p*16 + (0..15).
// A 128-row panel (8 rgs) = 32KB contiguous; staging stays 1:1 memcpy;
// all LDS/global fragment reads remain lane-contiguous 16B (conflict-free).

#define N_ROWS 8192
#define BSZ    4096
#define DIM    256
#define INV_TAU 2.0f
#define EPS_REF 1e-8f
#define COS_EPS 1e-8f
#define NG2     64                     // 128-row groups
#define NTILES  (NG2 * (NG2 + 1) / 2)  // 2080 triangular tiles
#define LSTRIDE 260                    // padded floats per row in knorm LDS

typedef __attribute__((ext_vector_type(4))) float f32x4;
typedef __attribute__((ext_vector_type(8))) int   v8i;
typedef union { int4 x[2]; v8i v; } frag32;

// sum across each 16-lane group via DPP row_ror (VALU pipe, no LDS traffic)
__device__ __forceinline__ float red16(float x) {
    x += __int_as_float(__builtin_amdgcn_update_dpp(0, __float_as_int(x), 0x121, 0xf, 0xf, false));
    x += __int_as_float(__builtin_amdgcn_update_dpp(0, __float_as_int(x), 0x122, 0xf, 0xf, false));
    x += __int_as_float(__builtin_amdgcn_update_dpp(0, __float_as_int(x), 0x124, 0xf, 0xf, false));
    x += __int_as_float(__builtin_amdgcn_update_dpp(0, __float_as_int(x), 0x128, 0xf, 0xf, false));
    return x;
}

// ---------------- Kernel 1: normalize + fp8 quantize + MX-fragment swizzle --
__global__ __launch_bounds__(256) void knorm(const float* __restrict__ zi,
                                             const float* __restrict__ zj,
                                             unsigned char* __restrict__ znsw,
                                             float* __restrict__ out) {
    __shared__ float lds[16 * LSTRIDE];
    __shared__ float nrm[16];
    const int rg = blockIdx.x;     // 0..511: 16-row group
    const int t  = threadIdx.x;
    const int w  = t >> 6;
    const int l  = t & 63;
    const int row0 = rg * 16;
    if (rg == 0 && t == 0) out[0] = 0.f;    // kfinal atomics run after us

    // load + register norms: iteration s -> row 4s+w, cols l*4..l*4+3
    #pragma unroll
    for (int s = 0; s < 4; ++s) {
        const int row = s * 4 + w;
        const int r   = row0 + row;
        const float* src = (r < BSZ) ? zi + (size_t)r * DIM + l * 4
                                     : zj + (size_t)(r - BSZ) * DIM + l * 4;
        const float4 v = *(const float4*)src;
        *(float4*)&lds[row * LSTRIDE + l * 4] = v;
        float ss = v.x*v.x + v.y*v.y + v.z*v.z + v.w*v.w;
        #pragma unroll
        for (int off = 32; off >= 1; off >>= 1) ss += __shfl_xor(ss, off);
        if (l == 0) nrm[row] = 1.0f / fmaxf(sqrtf(ss), COS_EPS);
    }
    __syncthreads();

    // quantize: thread t -> piece pi = t>>6 (h = pi>>1, p = pi&1), lane fl.
    // 16 consecutive k starting at h*128 + (fl>>4)*32 + p*16, row fl&15.
    const int pi = t >> 6, fl = t & 63;
    const int h = pi >> 1, p = pi & 1;
    const int r16 = fl & 15, q = fl >> 4;
    const int k0 = h * 128 + q * 32 + p * 16;
    const float inv = nrm[r16];
    float f[16];
    #pragma unroll
    for (int j = 0; j < 16; ++j) f[j] = lds[r16 * LSTRIDE + k0 + j] * inv;
    int wd[4];
    #pragma unroll
    for (int g = 0; g < 4; ++g) {
        int a = 0;
        a = __builtin_amdgcn_cvt_pk_fp8_f32(f[g*4+0], f[g*4+1], a, false);
        a = __builtin_amdgcn_cvt_pk_fp8_f32(f[g*4+2], f[g*4+3], a, true);
        wd[g] = a;
    }
    *(int4*)(znsw + (size_t)rg * 4096 + pi * 1024 + fl * 16) =
        make_int4(wd[0], wd[1], wd[2], wd[3]);
}

// ---------------- Kernel 2: triangular Gram; A staged, B direct, MX MFMA ----
__global__ __launch_bounds__(256, 2) void kgemm(const unsigned char* __restrict__ znsw,
                                                float* __restrict__ P,
                                                float* __restrict__ selfdot,
                                                float* __restrict__ pairdot) {
    __shared__ __align__(16) unsigned char pan[32768];   // A panel (all K)
    const int w = threadIdx.x >> 6;
    const int l = threadIdx.x & 63;

    // triangular decode over NG2=64: S(G) = G*(129-G)/2
    const int t = blockIdx.x;
    int Gi = (int)((129.0f - sqrtf(16641.0f - 8.0f * (float)t)) * 0.5f);
    while ((Gi + 1) * (129 - (Gi + 1)) / 2 <= t) ++Gi;
    while (Gi * (129 - Gi) / 2 > t) --Gi;
    const int Gj = Gi + (t - Gi * (129 - Gi) / 2);

    // stage A panel (32KB): 1:1 contiguous copy, 8 issues/thread
    const char* srcA = (const char*)znsw + (size_t)Gi * 32768;
    #pragma unroll
    for (int sub = 0; sub < 8; ++sub) {
        const int off = sub * 4096 + w * 1024;
        __builtin_amdgcn_global_load_lds(
            (const __attribute__((address_space(1))) void*)(srcA + off + l * 16),
            (__attribute__((address_space(3))) void*)(&pan[off]), 16, 0, 0);
    }

    // quadrant: rows (w>>1)*64 of A, cols (w&1)*64 of B
    const int rh = w >> 1, ch = w & 1;
    // B fragment global base for (nt, h, p): bbase + nt*4096 + h*2048 + p*1024
    const char* bbase = (const char*)znsw + (size_t)Gj * 32768 + ch * 4 * 4096 + l * 16;

    // prefetch B h=0 fragments before the barrier (drained together)
    frag32 B0[4], B1[4];
    #pragma unroll
    for (int nt = 0; nt < 4; ++nt) {
        B0[nt].x[0] = *(const int4*)(bbase + nt * 4096);
        B0[nt].x[1] = *(const int4*)(bbase + nt * 4096 + 1024);
    }

    f32x4 acc[4][4];
    #pragma unroll
    for (int mt = 0; mt < 4; ++mt)
        #pragma unroll
        for (int nt = 0; nt < 4; ++nt)
            acc[mt][nt] = (f32x4){0.f, 0.f, 0.f, 0.f};

    __syncthreads();   // A staged (B0 in flight -> drained here too)

    #pragma unroll
    for (int h = 0; h < 2; ++h) {
        if (h == 0) {   // prefetch second K-half of B
            #pragma unroll
            for (int nt = 0; nt < 4; ++nt) {
                B1[nt].x[0] = *(const int4*)(bbase + nt * 4096 + 2048);
                B1[nt].x[1] = *(const int4*)(bbase + nt * 4096 + 3072);
            }
        }
        frag32 A[4];
        #pragma unroll
        for (int mt = 0; mt < 4; ++mt) {
            const char* ap = (const char*)&pan[(rh * 4 + mt) * 4096 + h * 2048] + l * 16;
            A[mt].x[0] = *(const int4*)(ap);
            A[mt].x[1] = *(const int4*)(ap + 1024);
        }
        #pragma unroll
        for (int mt = 0; mt < 4; ++mt)
            #pragma unroll
            for (int nt = 0; nt < 4; ++nt) {
                const v8i bv = (h == 0) ? B0[nt].v : B1[nt].v;
                acc[mt][nt] = __builtin_amdgcn_mfma_scale_f32_16x16x128_f8f6f4(
                    A[mt].v, bv, acc[mt][nt],
                    0, 0,                     // cbsz=0 (fp8 e4m3), blgp=0 (fp8)
                    0, 0x7f7f7f7f,            // scale_a opsel, e8m0 1.0
                    0, 0x7f7f7f7f);           // scale_b opsel, e8m0 1.0
            }
    }

    // ---- wave-local epilogue (C/D layout: col = l&15, row = (l>>4)*4+reg) ----
    const int c = l & 15, q = l >> 4;
    const int rsel = c - 4 * q;
    const bool vld = (rsel >= 0) && (rsel < 4);

    // self/pair diagonals live in quadrants with rh==ch
    if ((Gi == Gj || Gj == Gi + 32) && rh == ch) {
        float dv[4];
        #pragma unroll
        for (int mt = 0; mt < 4; ++mt) {
            float d = acc[mt][mt][0];
            #pragma unroll
            for (int r = 1; r < 4; ++r)
                if (rsel == r) d = acc[mt][mt][r];
            dv[mt] = d;
        }
        if (vld) {
            float* dst = (Gi == Gj) ? selfdot : pairdot;
            #pragma unroll
            for (int mt = 0; mt < 4; ++mt)
                dst[Gi * 128 + rh * 64 + mt * 16 + c] = dv[mt];
        }
    }

    #pragma unroll
    for (int mt = 0; mt < 4; ++mt)
        #pragma unroll
        for (int nt = 0; nt < 4; ++nt)
            #pragma unroll
            for (int r = 0; r < 4; ++r)
                acc[mt][nt][r] = __expf(acc[mt][nt][r] * INV_TAU);

    // row sums (DPP reduce across 16 col lanes) -> P[Gj*2+ch][...]
    float rs[4][4];
    #pragma unroll
    for (int mt = 0; mt < 4; ++mt)
        #pragma unroll
        for (int r = 0; r < 4; ++r)
            rs[mt][r] = red16(acc[mt][0][r] + acc[mt][1][r] + acc[mt][2][r] + acc[mt][3][r]);
    if (c == 0) {
        #pragma unroll
        for (int mt = 0; mt < 4; ++mt) {
            const f32x4 o4 = (f32x4){rs[mt][0], rs[mt][1], rs[mt][2], rs[mt][3]};
            __builtin_nontemporal_store(o4,
                (f32x4*)&P[(size_t)(Gj * 2 + ch) * N_ROWS + Gi * 128 + rh * 64 + mt * 16 + q * 4]);
        }
    }

    // col sums (strictly-upper blocks) -> P[Gi*2+rh][Gj*128 + ch*64 + ...]
    if (Gi != Gj) {
        float cs[4];
        #pragma unroll
        for (int nt = 0; nt < 4; ++nt) {
            float s = 0.f;
            #pragma unroll
            for (int mt = 0; mt < 4; ++mt)
                #pragma unroll
                for (int r = 0; r < 4; ++r)
                    s += acc[mt][nt][r];
            s += __shfl_xor(s, 16);
            s += __shfl_xor(s, 32);
            cs[nt] = s;
        }
        if (q == 0) {
            #pragma unroll
            for (int nt = 0; nt < 4; ++nt)
                __builtin_nontemporal_store(cs[nt],
                    &P[(size_t)(Gi * 2 + rh) * N_ROWS + Gj * 128 + ch * 64 + nt * 16 + c]);
        }
    }
}

// ---------------- Kernel 3: per-row loss (latency-hiding) -------------------
__global__ __launch_bounds__(256) void kfinal(const float* __restrict__ P,
                                              const float* __restrict__ selfdot,
                                              const float* __restrict__ pairdot,
                                              float* __restrict__ out) {
    const int l = threadIdx.x & 63;        // row within block
    const int w = threadIdx.x >> 6;        // strip quarter
    const int row = blockIdx.x * 64 + l;
    float s = 0.f;
    #pragma unroll
    for (int st = 0; st < 32; ++st)
        s += P[(size_t)(w * 32 + st) * N_ROWS + row];
    __shared__ float wsum[4][64];
    wsum[w][l] = s;
    __syncthreads();
    if (w == 0) {
        const float tot = wsum[0][l] + wsum[1][l] + wsum[2][l] + wsum[3][l];
        const float selfe = __expf(selfdot[row] * INV_TAU);
        const float pd    = pairdot[(row < BSZ) ? row : row - BSZ];
        float loss = logf(tot - selfe + EPS_REF) - pd * INV_TAU;
        #pragma unroll
        for (int off = 32; off >= 1; off >>= 1) loss += __shfl_xor(loss, off);
        if (l == 0) atomicAdd(out, loss * (1.0f / (float)N_ROWS));
    }
}

extern "C" void kernel_launch(void* const* d_in, const int* in_sizes, int n_in,
                              void* d_out, int out_size, void* d_ws, size_t ws_size,
                              hipStream_t stream) {
    const float* zi = (const float*)d_in[0];
    const float* zj = (const float*)d_in[1];
    float* out = (float*)d_out;

    char* ws = (char*)d_ws;
    unsigned char* znsw = (unsigned char*)ws;                       // 2 MB
    float* P       = (float*)(ws + 2 * 1024 * 1024);                // 4 MB
    float* selfdot = (float*)(ws + 6 * 1024 * 1024);                // 32 KB
    float* pairdot = (float*)(ws + 6 * 1024 * 1024 + 32 * 1024);    // 16 KB

    knorm <<<N_ROWS / 16, 256, 0, stream>>>(zi, zj, znsw, out);
    kgemm <<<NTILES, 256, 0, stream>>>(znsw, P, selfdot, pairdot);
    kfinal<<<N_ROWS / 64, 256, 0, stream>>>(P, selfdot, pairdot, out);
}